// Round 3
// baseline (489.443 us; speedup 1.0000x reference)
//
#include <hip/hip_runtime.h>
#include <stdint.h>

// ---------------------------------------------------------------------------
// MHA forward, MI355X/gfx950. B=2 S=2048 D=1024 H=16 hd=64.
// Pipeline: cvt x -> bf16 | transpose W's -> bf16 [N][K] | QKV MFMA GEMM ->
// Q/K [bh][s][64] + V^T [bh][64][s] bf16 | flash attn (dbuf K/V, reg-prefetch
// mask via NAMED buffers — rule #20, defer-max, deferred row-sum) ->
// scrambled vals bf16 | out GEMM -> f32.
// ---------------------------------------------------------------------------

#define LOG2E 1.44269504088896340736f

typedef __attribute__((ext_vector_type(4))) float f32x4;
typedef __attribute__((ext_vector_type(8))) short short8v;
typedef __attribute__((ext_vector_type(8))) __bf16 bf16x8;

__device__ __forceinline__ unsigned short f2bf(float f) {
  unsigned u = __builtin_bit_cast(unsigned, f);
  u += 0x7FFFu + ((u >> 16) & 1u);  // RNE
  return (unsigned short)(u >> 16);
}

__device__ __forceinline__ unsigned pack2(float lo, float hi) {
  return (unsigned)f2bf(lo) | ((unsigned)f2bf(hi) << 16);
}

__device__ __forceinline__ f32x4 mfma16(short8v a, short8v b, f32x4 c) {
  return __builtin_amdgcn_mfma_f32_16x16x32_bf16(
      __builtin_bit_cast(bf16x8, a), __builtin_bit_cast(bf16x8, b), c, 0, 0, 0);
}

// async global->LDS, 16 bytes per lane. LDS dest = wave-uniform base + lane*16.
__device__ __forceinline__ void gload_lds16(const void* g, void* l) {
  __builtin_amdgcn_global_load_lds(
      (const __attribute__((address_space(1))) void*)(uintptr_t)g,
      (__attribute__((address_space(3))) void*)(uintptr_t)l, 16, 0, 0);
}

// ---------------------------------------------------------------------------
__global__ void cvt_x_kernel(const float4* __restrict__ src,
                             uint2* __restrict__ dst, int n4) {
  int i = blockIdx.x * 256 + threadIdx.x;
  if (i < n4) {
    float4 v = src[i];
    dst[i] = make_uint2(pack2(v.x, v.y), pack2(v.z, v.w));
  }
}

// f32 [R][C] -> bf16 [C][R]
__global__ void transpose_cvt_kernel(const float* __restrict__ src,
                                     unsigned short* __restrict__ dst,
                                     int R, int C) {
  __shared__ unsigned short tile[64][65];
  int tc = threadIdx.x & 63;
  int tr = threadIdx.x >> 6;
  int c0 = blockIdx.x * 64;
  int r0 = blockIdx.y * 64;
#pragma unroll
  for (int i = 0; i < 16; ++i) {
    int r = tr * 16 + i;
    tile[r][tc] = f2bf(src[(size_t)(r0 + r) * C + c0 + tc]);
  }
  __syncthreads();
#pragma unroll
  for (int i = 0; i < 16; ++i) {
    int cc = tr * 16 + i;
    dst[(size_t)(c0 + cc) * R + r0 + tc] = tile[tc][cc];
  }
}

// ---------------------------------------------------------------------------
// QKV GEMM: [4096,1024]bf16 @ WT[3072,1024]bf16 + bias -> Q/K [bh][2048][64],
// V^T [bh][64][2048], all bf16. 128x128 tile, BK=64, 4 waves (2x2 of 64x64).
__global__ __launch_bounds__(256, 2)
void gemm_qkv_kernel(const unsigned short* __restrict__ xbf,
                     const unsigned short* __restrict__ WT,
                     const float* __restrict__ bias,
                     unsigned short* __restrict__ Qb,
                     unsigned short* __restrict__ Kb,
                     unsigned short* __restrict__ VbT) {
  const int K = 1024;
  __shared__ __align__(16) unsigned short As[128 * 64];
  __shared__ __align__(16) unsigned short Bs[128 * 64];
  int tid = threadIdx.x;
  int lane = tid & 63;
  int wid = tid >> 6;
  int m0 = blockIdx.y * 128;
  int n0 = blockIdx.x * 128;
  int wm = (wid >> 1) * 64;
  int wn = (wid & 1) * 64;
  f32x4 acc[4][4] = {};
  for (int k0 = 0; k0 < K; k0 += 64) {
#pragma unroll
    for (int it = 0; it < 4; ++it) {
      int G = it * 256 + tid;
      int r = G >> 3, g = G & 7;
      int sg = g ^ (r & 7);  // inverse-swizzled source, linear LDS dest
      gload_lds16(xbf + (size_t)(m0 + r) * K + k0 + sg * 8, &As[G * 8]);
      gload_lds16(WT + (size_t)(n0 + r) * K + k0 + sg * 8, &Bs[G * 8]);
    }
    __syncthreads();
#pragma unroll
    for (int ks = 0; ks < 2; ++ks) {
      short8v a[4], bf[4];
      int kg = ks * 4 + (lane >> 4);
#pragma unroll
      for (int i = 0; i < 4; ++i) {
        int ra = wm + i * 16 + (lane & 15);
        a[i] = *(const short8v*)&As[ra * 64 + ((kg ^ (ra & 7)) << 3)];
        int rb = wn + i * 16 + (lane & 15);
        bf[i] = *(const short8v*)&Bs[rb * 64 + ((kg ^ (rb & 7)) << 3)];
      }
#pragma unroll
      for (int i = 0; i < 4; ++i)
#pragma unroll
        for (int j = 0; j < 4; ++j)
          acc[i][j] = mfma16(a[i], bf[j], acc[i][j]);
    }
    __syncthreads();
  }
  // epilogue: n -> (h, t, d); t=0 Q, t=1 K, t=2 V(transposed)
#pragma unroll
  for (int i = 0; i < 4; ++i) {
#pragma unroll
    for (int j = 0; j < 4; ++j) {
      int n = n0 + wn + j * 16 + (lane & 15);
      float bv = bias[n];
      int h = n / 192;
      int rr = n - h * 192;
      int t = rr >> 6;
      int d = rr & 63;
#pragma unroll
      for (int rg = 0; rg < 4; ++rg) {
        int m = m0 + wm + i * 16 + ((lane >> 4) << 2) + rg;
        int b = m >> 11, s = m & 2047;
        unsigned short val = f2bf(acc[i][j][rg] + bv);
        int bh = b * 16 + h;
        if (t == 2) {
          VbT[((size_t)bh * 64 + d) * 2048 + s] = val;
        } else {
          unsigned short* dst = (t == 0) ? Qb : Kb;
          dst[((size_t)bh * 2048 + s) * 64 + d] = val;
        }
      }
    }
  }
}

// ---------------------------------------------------------------------------
// Flash attention. Block = (b,h,qtile of 64). 4 waves x 16 q-rows each.
// Double-buffered K/V stage; mask prefetched into NAMED register buffers
// (mbA/mbB swapped via inlined lambda with literal `cur` — avoids the
// runtime-indexed-private-array scratch demotion that cost R2 2.2x).
__global__ __launch_bounds__(256, 4)
void attn_kernel(const unsigned short* __restrict__ Qb,
                 const unsigned short* __restrict__ Kb,
                 const unsigned short* __restrict__ VbT,
                 const float* __restrict__ mask,
                 unsigned short* __restrict__ vals) {
  __shared__ __align__(16) unsigned short Ks[2][64 * 64];
  __shared__ __align__(16) unsigned short Vs[2][64 * 64];
  __shared__ __align__(16) unsigned short Ps[4][16 * 64];
  int tid = threadIdx.x;
  int lane = tid & 63;
  int wid = tid >> 6;
  int h = blockIdx.x & 15;          // h innermost: mask tile L2 reuse
  int qt = (blockIdx.x >> 4) & 31;
  int b = blockIdx.x >> 9;
  int bh = b * 16 + h;
  size_t bh_off = (size_t)bh * 2048 * 64;
  int q0 = qt * 64 + wid * 16;

  const unsigned short* qptr =
      Qb + bh_off + (size_t)(q0 + (lane & 15)) * 64 + ((lane >> 4) << 3);
  short8v qa0 = *(const short8v*)qptr;
  short8v qa1 = *(const short8v*)(qptr + 32);

  f32x4 o[4] = {};
  float m_run[4], l_lane[4], mL[4];
#pragma unroll
  for (int r = 0; r < 4; ++r) { m_run[r] = -1e30f; l_lane[r] = 0.f; mL[r] = 0.f; }

  const float* mrow =
      mask + ((size_t)b * 2048 + q0 + ((lane >> 4) << 2)) * 2048 + (lane & 15);

  auto stage = [&](int kt, int bi) {
#pragma unroll
    for (int it = 0; it < 2; ++it) {
      int G = it * 256 + tid;
      int r = G >> 3, g = G & 7;
      int sg = g ^ (r & 7);
      gload_lds16(Kb + bh_off + (size_t)(kt * 64 + r) * 64 + sg * 8,
                  &Ks[bi][G * 8]);
      gload_lds16(VbT + bh_off + (size_t)r * 2048 + kt * 64 + sg * 8,
                  &Vs[bi][G * 8]);
    }
  };

  const float THR = 4.0f;

  // tile body: all private-array indices static after inlining; `cur` literal.
  auto tile_body = [&](int kt, const float (&mcur)[4][4], float (&mnxt)[4][4],
                       int cur) {
    // prefetch next tile: K/V -> LDS (other buffer), mask -> named registers
    if (kt < 31) {
      stage(kt + 1, cur ^ 1);
      const float* mp = mrow + (size_t)(kt + 1) * 64;
#pragma unroll
      for (int f = 0; f < 4; ++f)
#pragma unroll
        for (int r = 0; r < 4; ++r)
          mnxt[f][r] = mp[(size_t)r * 2048 + f * 16];
    }

    // QK^T -> sf[f]: rows q=(lane>>4)*4+reg, col k = f*16 + (lane&15)
    f32x4 sf[4] = {};
#pragma unroll
    for (int ks = 0; ks < 2; ++ks) {
      short8v qa = ks ? qa1 : qa0;
      int kg = ks * 4 + (lane >> 4);
#pragma unroll
      for (int f = 0; f < 4; ++f) {
        int row = f * 16 + (lane & 15);
        short8v kb =
            *(const short8v*)&Ks[cur][row * 64 + ((kg ^ (row & 7)) << 3)];
        sf[f] = mfma16(qa, kb, sf[f]);
      }
    }

    // sc = qk*scale + mask (in-place in sf); per-row tile max
    float mt[4];
#pragma unroll
    for (int f = 0; f < 4; ++f)
#pragma unroll
      for (int r = 0; r < 4; ++r)
        sf[f][r] = fmaf(sf[f][r], 0.125f, mcur[f][r]);
#pragma unroll
    for (int r = 0; r < 4; ++r)
      mt[r] = fmaxf(fmaxf(sf[0][r], sf[1][r]), fmaxf(sf[2][r], sf[3][r]));
#pragma unroll
    for (int xm = 1; xm < 16; xm <<= 1)
#pragma unroll
      for (int r = 0; r < 4; ++r) mt[r] = fmaxf(mt[r], __shfl_xor(mt[r], xm));

    // defer-max: only rescale when some row's max grew past THR
    bool ok = (mt[0] <= m_run[0] + THR) && (mt[1] <= m_run[1] + THR) &&
              (mt[2] <= m_run[2] + THR) && (mt[3] <= m_run[3] + THR);
    if (!__all(ok)) {
#pragma unroll
      for (int r = 0; r < 4; ++r) {
        float mn = fmaxf(m_run[r], mt[r]);
        float al = exp2f((m_run[r] - mn) * LOG2E);
        m_run[r] = mn;
        mL[r] = mn * LOG2E;
        l_lane[r] *= al;
#pragma unroll
        for (int f = 0; f < 4; ++f) o[f][r] *= al;
      }
    }

    // p = exp2(sc*log2e - m*log2e); per-lane partial row-sum (deferred reduce)
    unsigned short pb[4][4];
#pragma unroll
    for (int f = 0; f < 4; ++f)
#pragma unroll
      for (int r = 0; r < 4; ++r) {
        float p = exp2f(fmaf(sf[f][r], LOG2E, -mL[r]));
        l_lane[r] += p;
        pb[f][r] = f2bf(p);
      }

    // transpose P through per-wave swizzled LDS (wave-private: no barrier)
#pragma unroll
    for (int f = 0; f < 4; ++f)
#pragma unroll
      for (int r = 0; r < 4; ++r) {
        int prow = ((lane >> 4) << 2) + r;
        int pcol = f * 16 + (lane & 15);
        Ps[wid][prow * 64 + (((pcol >> 3) ^ (prow & 7)) << 3) + (pcol & 7)] =
            pb[f][r];
      }
    // PV: o[f] rows q, col d = f*16 + (lane&15)
#pragma unroll
    for (int ks = 0; ks < 2; ++ks) {
      int arow = lane & 15;
      int kg = ks * 4 + (lane >> 4);
      short8v pa =
          *(const short8v*)&Ps[wid][arow * 64 + ((kg ^ (arow & 7)) << 3)];
#pragma unroll
      for (int f = 0; f < 4; ++f) {
        int vrow = f * 16 + (lane & 15);
        short8v vb =
            *(const short8v*)&Vs[cur][vrow * 64 + ((kg ^ (vrow & 7)) << 3)];
        o[f] = mfma16(pa, vb, o[f]);
      }
    }
    __syncthreads();
  };

  // prologue: mask tile 0 -> mbA, K/V tile 0 -> LDS buf 0
  float mbA[4][4], mbB[4][4];
#pragma unroll
  for (int f = 0; f < 4; ++f)
#pragma unroll
    for (int r = 0; r < 4; ++r)
      mbA[f][r] = mrow[(size_t)r * 2048 + f * 16];
  stage(0, 0);
  __syncthreads();

  for (int t = 0; t < 16; ++t) {
    tile_body(2 * t,     mbA, mbB, 0);
    tile_body(2 * t + 1, mbB, mbA, 1);
  }

  // deferred row-sum reduction
#pragma unroll
  for (int xm = 1; xm < 16; xm <<= 1)
#pragma unroll
    for (int r = 0; r < 4; ++r) l_lane[r] += __shfl_xor(l_lane[r], xm);
  float rinv[4];
#pragma unroll
  for (int r = 0; r < 4; ++r) rinv[r] = 1.0f / l_lane[r];

  // epilogue: scrambled reshape (b,h,s,d) -> (b, h*128 + s/16, (s%16)*64 + d)
#pragma unroll
  for (int f = 0; f < 4; ++f)
#pragma unroll
    for (int r = 0; r < 4; ++r) {
      int s = q0 + ((lane >> 4) << 2) + r;
      int d = f * 16 + (lane & 15);
      int s2 = h * 128 + (s >> 4);
      int c2 = ((s & 15) << 6) + d;
      vals[((size_t)b * 2048 + s2) * 1024 + c2] = f2bf(o[f][r] * rinv[r]);
    }
}

// ---------------------------------------------------------------------------
// Output GEMM: vals[4096,1024]bf16 @ WoT[1024,1024]bf16 + bo -> out f32
__global__ __launch_bounds__(256, 2)
void gemm_out_kernel(const unsigned short* __restrict__ vals,
                     const unsigned short* __restrict__ WoT,
                     const float* __restrict__ bo,
                     float* __restrict__ out) {
  const int K = 1024;
  __shared__ __align__(16) unsigned short As[128 * 64];
  __shared__ __align__(16) unsigned short Bs[128 * 64];
  int tid = threadIdx.x;
  int lane = tid & 63;
  int wid = tid >> 6;
  int m0 = blockIdx.y * 128;
  int n0 = blockIdx.x * 128;
  int wm = (wid >> 1) * 64;
  int wn = (wid & 1) * 64;
  f32x4 acc[4][4] = {};
  for (int k0 = 0; k0 < K; k0 += 64) {
#pragma unroll
    for (int it = 0; it < 4; ++it) {
      int G = it * 256 + tid;
      int r = G >> 3, g = G & 7;
      int sg = g ^ (r & 7);
      gload_lds16(vals + (size_t)(m0 + r) * K + k0 + sg * 8, &As[G * 8]);
      gload_lds16(WoT + (size_t)(n0 + r) * K + k0 + sg * 8, &Bs[G * 8]);
    }
    __syncthreads();
#pragma unroll
    for (int ks = 0; ks < 2; ++ks) {
      short8v a[4], bf[4];
      int kg = ks * 4 + (lane >> 4);
#pragma unroll
      for (int i = 0; i < 4; ++i) {
        int ra = wm + i * 16 + (lane & 15);
        a[i] = *(const short8v*)&As[ra * 64 + ((kg ^ (ra & 7)) << 3)];
        int rb = wn + i * 16 + (lane & 15);
        bf[i] = *(const short8v*)&Bs[rb * 64 + ((kg ^ (rb & 7)) << 3)];
      }
#pragma unroll
      for (int i = 0; i < 4; ++i)
#pragma unroll
        for (int j = 0; j < 4; ++j)
          acc[i][j] = mfma16(a[i], bf[j], acc[i][j]);
    }
    __syncthreads();
  }
#pragma unroll
  for (int i = 0; i < 4; ++i) {
#pragma unroll
    for (int j = 0; j < 4; ++j) {
      int n = n0 + wn + j * 16 + (lane & 15);
      float bv = bo[n];
#pragma unroll
      for (int rg = 0; rg < 4; ++rg) {
        int m = m0 + wm + i * 16 + ((lane >> 4) << 2) + rg;
        out[(size_t)m * 1024 + n] = acc[i][j][rg] + bv;
      }
    }
  }
}

// ---------------------------------------------------------------------------
extern "C" void kernel_launch(void* const* d_in, const int* in_sizes, int n_in,
                              void* d_out, int out_size, void* d_ws,
                              size_t ws_size, hipStream_t stream) {
  const float* x    = (const float*)d_in[0];
  const float* mask = (const float*)d_in[1];
  const float* Wqkv = (const float*)d_in[2];
  const float* bqkv = (const float*)d_in[3];
  const float* Wo   = (const float*)d_in[4];
  const float* bo   = (const float*)d_in[5];
  float* out = (float*)d_out;

  char* ws = (char*)d_ws;
  // layout (bytes): xbf 8M | WqkvT 6M | WoT 2M | Qb 8M | Kb 8M | VbT 8M
  // vals aliases xbf (x dead after gemm_qkv). Total 40 MB.
  unsigned short* xbf   = (unsigned short*)(ws);
  unsigned short* WqkvT = (unsigned short*)(ws + 8388608);
  unsigned short* WoT   = (unsigned short*)(ws + 14680064);
  unsigned short* Qb    = (unsigned short*)(ws + 16777216);
  unsigned short* Kb    = (unsigned short*)(ws + 25165824);
  unsigned short* VbT   = (unsigned short*)(ws + 33554432);
  unsigned short* vals  = xbf;  // reuse

  hipLaunchKernelGGL(cvt_x_kernel, dim3(4096), dim3(256), 0, stream,
                     (const float4*)x, (uint2*)xbf, 1048576);
  hipLaunchKernelGGL(transpose_cvt_kernel, dim3(48, 16), dim3(256), 0, stream,
                     Wqkv, WqkvT, 1024, 3072);
  hipLaunchKernelGGL(transpose_cvt_kernel, dim3(16, 16), dim3(256), 0, stream,
                     Wo, WoT, 1024, 1024);
  hipLaunchKernelGGL(gemm_qkv_kernel, dim3(24, 32), dim3(256), 0, stream,
                     xbf, WqkvT, bqkv, Qb, Kb, VbT);
  hipLaunchKernelGGL(attn_kernel, dim3(1024), dim3(256), 0, stream,
                     Qb, Kb, VbT, mask, vals);
  hipLaunchKernelGGL(gemm_out_kernel, dim3(8, 32), dim3(256), 0, stream,
                     vals, WoT, bo, out);
}

// Round 5
// 276.882 us; speedup vs baseline: 1.7677x; 1.7677x over previous
//
#include <hip/hip_runtime.h>
#include <stdint.h>

// ---------------------------------------------------------------------------
// MHA forward, MI355X/gfx950. B=2 S=2048 D=1024 H=16 hd=64.
// Pipeline: cvt x -> bf16 | transpose W's -> bf16 [N][K] | QKV MFMA GEMM ->
// Q/K [bh][s][64] + V^T [bh][64][s] bf16 | flash attn (macro-expanded tile
// body: NO lambdas -> no scratch; dbuf K/V; defer-max; deferred row-sum) ->
// scrambled vals bf16 | out GEMM -> f32.
// ---------------------------------------------------------------------------

#define LOG2E 1.44269504088896340736f

typedef __attribute__((ext_vector_type(4))) float f32x4;
typedef __attribute__((ext_vector_type(8))) short short8v;
typedef __attribute__((ext_vector_type(8))) __bf16 bf16x8;

__device__ __forceinline__ unsigned short f2bf(float f) {
  unsigned u = __builtin_bit_cast(unsigned, f);
  u += 0x7FFFu + ((u >> 16) & 1u);  // RNE
  return (unsigned short)(u >> 16);
}

__device__ __forceinline__ unsigned pack2(float lo, float hi) {
  return (unsigned)f2bf(lo) | ((unsigned)f2bf(hi) << 16);
}

__device__ __forceinline__ f32x4 mfma16(short8v a, short8v b, f32x4 c) {
  return __builtin_amdgcn_mfma_f32_16x16x32_bf16(
      __builtin_bit_cast(bf16x8, a), __builtin_bit_cast(bf16x8, b), c, 0, 0, 0);
}

// async global->LDS, 16 bytes per lane. LDS dest = wave-uniform base + lane*16.
__device__ __forceinline__ void gload_lds16(const void* g, void* l) {
  __builtin_amdgcn_global_load_lds(
      (const __attribute__((address_space(1))) void*)(uintptr_t)g,
      (__attribute__((address_space(3))) void*)(uintptr_t)l, 16, 0, 0);
}

// ---------------------------------------------------------------------------
__global__ void cvt_x_kernel(const float4* __restrict__ src,
                             uint2* __restrict__ dst, int n4) {
  int i = blockIdx.x * 256 + threadIdx.x;
  if (i < n4) {
    float4 v = src[i];
    dst[i] = make_uint2(pack2(v.x, v.y), pack2(v.z, v.w));
  }
}

// f32 [R][C] -> bf16 [C][R]
__global__ void transpose_cvt_kernel(const float* __restrict__ src,
                                     unsigned short* __restrict__ dst,
                                     int R, int C) {
  __shared__ unsigned short tile[64][65];
  int tc = threadIdx.x & 63;
  int tr = threadIdx.x >> 6;
  int c0 = blockIdx.x * 64;
  int r0 = blockIdx.y * 64;
#pragma unroll
  for (int i = 0; i < 16; ++i) {
    int r = tr * 16 + i;
    tile[r][tc] = f2bf(src[(size_t)(r0 + r) * C + c0 + tc]);
  }
  __syncthreads();
#pragma unroll
  for (int i = 0; i < 16; ++i) {
    int cc = tr * 16 + i;
    dst[(size_t)(c0 + cc) * R + r0 + tc] = tile[tc][cc];
  }
}

// ---------------------------------------------------------------------------
// QKV GEMM: [4096,1024]bf16 @ WT[3072,1024]bf16 + bias -> Q/K [bh][2048][64],
// V^T [bh][64][2048], all bf16. 128x128 tile, BK=64, 4 waves (2x2 of 64x64).
__global__ __launch_bounds__(256, 2)
void gemm_qkv_kernel(const unsigned short* __restrict__ xbf,
                     const unsigned short* __restrict__ WT,
                     const float* __restrict__ bias,
                     unsigned short* __restrict__ Qb,
                     unsigned short* __restrict__ Kb,
                     unsigned short* __restrict__ VbT) {
  const int K = 1024;
  __shared__ __align__(16) unsigned short As[128 * 64];
  __shared__ __align__(16) unsigned short Bs[128 * 64];
  int tid = threadIdx.x;
  int lane = tid & 63;
  int wid = tid >> 6;
  int m0 = blockIdx.y * 128;
  int n0 = blockIdx.x * 128;
  int wm = (wid >> 1) * 64;
  int wn = (wid & 1) * 64;
  f32x4 acc[4][4] = {};
  for (int k0 = 0; k0 < K; k0 += 64) {
#pragma unroll
    for (int it = 0; it < 4; ++it) {
      int G = it * 256 + tid;
      int r = G >> 3, g = G & 7;
      int sg = g ^ (r & 7);  // inverse-swizzled source, linear LDS dest
      gload_lds16(xbf + (size_t)(m0 + r) * K + k0 + sg * 8, &As[G * 8]);
      gload_lds16(WT + (size_t)(n0 + r) * K + k0 + sg * 8, &Bs[G * 8]);
    }
    __syncthreads();
#pragma unroll
    for (int ks = 0; ks < 2; ++ks) {
      short8v a[4], bf[4];
      int kg = ks * 4 + (lane >> 4);
#pragma unroll
      for (int i = 0; i < 4; ++i) {
        int ra = wm + i * 16 + (lane & 15);
        a[i] = *(const short8v*)&As[ra * 64 + ((kg ^ (ra & 7)) << 3)];
        int rb = wn + i * 16 + (lane & 15);
        bf[i] = *(const short8v*)&Bs[rb * 64 + ((kg ^ (rb & 7)) << 3)];
      }
#pragma unroll
      for (int i = 0; i < 4; ++i)
#pragma unroll
        for (int j = 0; j < 4; ++j)
          acc[i][j] = mfma16(a[i], bf[j], acc[i][j]);
    }
    __syncthreads();
  }
  // epilogue: n -> (h, t, d); t=0 Q, t=1 K, t=2 V(transposed)
#pragma unroll
  for (int i = 0; i < 4; ++i) {
#pragma unroll
    for (int j = 0; j < 4; ++j) {
      int n = n0 + wn + j * 16 + (lane & 15);
      float bv = bias[n];
      int h = n / 192;
      int rr = n - h * 192;
      int t = rr >> 6;
      int d = rr & 63;
#pragma unroll
      for (int rg = 0; rg < 4; ++rg) {
        int m = m0 + wm + i * 16 + ((lane >> 4) << 2) + rg;
        int b = m >> 11, s = m & 2047;
        unsigned short val = f2bf(acc[i][j][rg] + bv);
        int bh = b * 16 + h;
        if (t == 2) {
          VbT[((size_t)bh * 64 + d) * 2048 + s] = val;
        } else {
          unsigned short* dst = (t == 0) ? Qb : Kb;
          dst[((size_t)bh * 2048 + s) * 64 + d] = val;
        }
      }
    }
  }
}

// ---------------------------------------------------------------------------
// Flash attention. Block = (b,h,qtile of 64). 4 waves x 16 q-rows each.
// Tile body is a MACRO (literal buffer index, fully static private indices):
// no function-call boundary, no runtime-indexed private arrays -> no scratch.

#define ATTN_STAGE(kt_, bi_)                                                  \
  do {                                                                        \
    _Pragma("unroll") for (int it_ = 0; it_ < 2; ++it_) {                     \
      int G_ = it_ * 256 + tid;                                               \
      int r_ = G_ >> 3, g_ = G_ & 7;                                          \
      int sg_ = g_ ^ (r_ & 7);                                                \
      gload_lds16(Kb + bh_off + (size_t)((kt_)*64 + r_) * 64 + sg_ * 8,       \
                  &Ks[bi_][G_ * 8]);                                          \
      gload_lds16(VbT + bh_off + (size_t)r_ * 2048 + (kt_)*64 + sg_ * 8,      \
                  &Vs[bi_][G_ * 8]);                                          \
    }                                                                         \
  } while (0)

#define ATTN_TILE(kt_, CUR_)                                                  \
  do {                                                                        \
    if ((kt_) < 31) ATTN_STAGE((kt_) + 1, (CUR_) ^ 1);                        \
    /* mask tile -> registers; loads issue before QK^T, overlap MFMA */       \
    const float* mp_ = mrow + (size_t)(kt_)*64;                               \
    float mk_[4][4];                                                          \
    _Pragma("unroll") for (int f = 0; f < 4; ++f)                             \
        _Pragma("unroll") for (int r = 0; r < 4; ++r)                         \
            mk_[f][r] = mp_[(size_t)r * 2048 + f * 16];                       \
    /* QK^T: rows q=(lane>>4)*4+reg, col k = f*16+(lane&15) */                \
    f32x4 sf[4] = {};                                                         \
    _Pragma("unroll") for (int ks = 0; ks < 2; ++ks) {                        \
      short8v qa = ks ? qa1 : qa0;                                            \
      int kg = ks * 4 + (lane >> 4);                                          \
      _Pragma("unroll") for (int f = 0; f < 4; ++f) {                         \
        int row = f * 16 + (lane & 15);                                       \
        short8v kb =                                                          \
            *(const short8v*)&Ks[CUR_][row * 64 + ((kg ^ (row & 7)) << 3)];   \
        sf[f] = mfma16(qa, kb, sf[f]);                                        \
      }                                                                       \
    }                                                                         \
    /* sc = qk*scale + mask; per-row tile max */                              \
    float mt_[4];                                                             \
    _Pragma("unroll") for (int f = 0; f < 4; ++f)                             \
        _Pragma("unroll") for (int r = 0; r < 4; ++r)                         \
            sf[f][r] = fmaf(sf[f][r], 0.125f, mk_[f][r]);                     \
    _Pragma("unroll") for (int r = 0; r < 4; ++r)                             \
        mt_[r] = fmaxf(fmaxf(sf[0][r], sf[1][r]), fmaxf(sf[2][r], sf[3][r])); \
    _Pragma("unroll") for (int xm = 1; xm < 16; xm <<= 1)                     \
        _Pragma("unroll") for (int r = 0; r < 4; ++r)                         \
            mt_[r] = fmaxf(mt_[r], __shfl_xor(mt_[r], xm));                   \
    /* defer-max: rescale only when some row max grew past THR */             \
    bool ok_ = (mt_[0] <= m_run[0] + THR) && (mt_[1] <= m_run[1] + THR) &&    \
               (mt_[2] <= m_run[2] + THR) && (mt_[3] <= m_run[3] + THR);      \
    if (!__all(ok_)) {                                                        \
      _Pragma("unroll") for (int r = 0; r < 4; ++r) {                         \
        float mn_ = fmaxf(m_run[r], mt_[r]);                                  \
        float al_ = exp2f((m_run[r] - mn_) * LOG2E);                          \
        m_run[r] = mn_;                                                       \
        mL[r] = mn_ * LOG2E;                                                  \
        l_lane[r] *= al_;                                                     \
        _Pragma("unroll") for (int f = 0; f < 4; ++f) o[f][r] *= al_;         \
      }                                                                       \
    }                                                                         \
    /* p = exp2(sc*log2e - mL); per-lane partial row-sum */                   \
    unsigned short pb_[4][4];                                                 \
    _Pragma("unroll") for (int f = 0; f < 4; ++f)                             \
        _Pragma("unroll") for (int r = 0; r < 4; ++r) {                       \
      float p_ = exp2f(fmaf(sf[f][r], LOG2E, -mL[r]));                        \
      l_lane[r] += p_;                                                        \
      pb_[f][r] = f2bf(p_);                                                   \
    }                                                                         \
    /* transpose P through per-wave swizzled LDS (wave-private) */            \
    _Pragma("unroll") for (int f = 0; f < 4; ++f)                             \
        _Pragma("unroll") for (int r = 0; r < 4; ++r) {                       \
      int prow_ = ((lane >> 4) << 2) + r;                                     \
      int pcol_ = f * 16 + (lane & 15);                                       \
      Ps[wid][prow_ * 64 + (((pcol_ >> 3) ^ (prow_ & 7)) << 3) +              \
              (pcol_ & 7)] = pb_[f][r];                                       \
    }                                                                         \
    /* PV: o[f] rows q, col d = f*16+(lane&15) */                             \
    _Pragma("unroll") for (int ks = 0; ks < 2; ++ks) {                        \
      int arow_ = lane & 15;                                                  \
      int kg = ks * 4 + (lane >> 4);                                          \
      short8v pa =                                                            \
          *(const short8v*)&Ps[wid][arow_ * 64 + ((kg ^ (arow_ & 7)) << 3)];  \
      _Pragma("unroll") for (int f = 0; f < 4; ++f) {                         \
        int vrow_ = f * 16 + (lane & 15);                                     \
        short8v vb =                                                          \
            *(const short8v*)&Vs[CUR_][vrow_ * 64 + ((kg ^ (vrow_ & 7)) << 3)]; \
        o[f] = mfma16(pa, vb, o[f]);                                          \
      }                                                                       \
    }                                                                         \
    __syncthreads();                                                          \
  } while (0)

__global__ __launch_bounds__(256, 4)
void attn_kernel(const unsigned short* __restrict__ Qb,
                 const unsigned short* __restrict__ Kb,
                 const unsigned short* __restrict__ VbT,
                 const float* __restrict__ mask,
                 unsigned short* __restrict__ vals) {
  __shared__ __align__(16) unsigned short Ks[2][64 * 64];
  __shared__ __align__(16) unsigned short Vs[2][64 * 64];
  __shared__ __align__(16) unsigned short Ps[4][16 * 64];
  int tid = threadIdx.x;
  int lane = tid & 63;
  int wid = tid >> 6;
  int h = blockIdx.x & 15;          // h innermost: mask tile L2 reuse
  int qt = (blockIdx.x >> 4) & 31;
  int b = blockIdx.x >> 9;
  int bh = b * 16 + h;
  size_t bh_off = (size_t)bh * 2048 * 64;
  int q0 = qt * 64 + wid * 16;

  const unsigned short* qptr =
      Qb + bh_off + (size_t)(q0 + (lane & 15)) * 64 + ((lane >> 4) << 3);
  short8v qa0 = *(const short8v*)qptr;
  short8v qa1 = *(const short8v*)(qptr + 32);

  f32x4 o[4] = {};
  float m_run[4], l_lane[4], mL[4];
#pragma unroll
  for (int r = 0; r < 4; ++r) { m_run[r] = -1e30f; l_lane[r] = 0.f; mL[r] = 0.f; }

  const float* mrow =
      mask + ((size_t)b * 2048 + q0 + ((lane >> 4) << 2)) * 2048 + (lane & 15);

  const float THR = 4.0f;

  ATTN_STAGE(0, 0);
  __syncthreads();

  for (int t = 0; t < 16; ++t) {
    ATTN_TILE(2 * t, 0);
    ATTN_TILE(2 * t + 1, 1);
  }

  // deferred row-sum reduction
#pragma unroll
  for (int xm = 1; xm < 16; xm <<= 1)
#pragma unroll
    for (int r = 0; r < 4; ++r) l_lane[r] += __shfl_xor(l_lane[r], xm);
  float rinv[4];
#pragma unroll
  for (int r = 0; r < 4; ++r) rinv[r] = 1.0f / l_lane[r];

  // epilogue: scrambled reshape (b,h,s,d) -> (b, h*128 + s/16, (s%16)*64 + d)
#pragma unroll
  for (int f = 0; f < 4; ++f)
#pragma unroll
    for (int r = 0; r < 4; ++r) {
      int s = q0 + ((lane >> 4) << 2) + r;
      int d = f * 16 + (lane & 15);
      int s2 = h * 128 + (s >> 4);
      int c2 = ((s & 15) << 6) + d;
      vals[((size_t)b * 2048 + s2) * 1024 + c2] = f2bf(o[f][r] * rinv[r]);
    }
}

// ---------------------------------------------------------------------------
// Output GEMM: vals[4096,1024]bf16 @ WoT[1024,1024]bf16 + bo -> out f32
__global__ __launch_bounds__(256, 2)
void gemm_out_kernel(const unsigned short* __restrict__ vals,
                     const unsigned short* __restrict__ WoT,
                     const float* __restrict__ bo,
                     float* __restrict__ out) {
  const int K = 1024;
  __shared__ __align__(16) unsigned short As[128 * 64];
  __shared__ __align__(16) unsigned short Bs[128 * 64];
  int tid = threadIdx.x;
  int lane = tid & 63;
  int wid = tid >> 6;
  int m0 = blockIdx.y * 128;
  int n0 = blockIdx.x * 128;
  int wm = (wid >> 1) * 64;
  int wn = (wid & 1) * 64;
  f32x4 acc[4][4] = {};
  for (int k0 = 0; k0 < K; k0 += 64) {
#pragma unroll
    for (int it = 0; it < 4; ++it) {
      int G = it * 256 + tid;
      int r = G >> 3, g = G & 7;
      int sg = g ^ (r & 7);
      gload_lds16(vals + (size_t)(m0 + r) * K + k0 + sg * 8, &As[G * 8]);
      gload_lds16(WoT + (size_t)(n0 + r) * K + k0 + sg * 8, &Bs[G * 8]);
    }
    __syncthreads();
#pragma unroll
    for (int ks = 0; ks < 2; ++ks) {
      short8v a[4], bf[4];
      int kg = ks * 4 + (lane >> 4);
#pragma unroll
      for (int i = 0; i < 4; ++i) {
        int ra = wm + i * 16 + (lane & 15);
        a[i] = *(const short8v*)&As[ra * 64 + ((kg ^ (ra & 7)) << 3)];
        int rb = wn + i * 16 + (lane & 15);
        bf[i] = *(const short8v*)&Bs[rb * 64 + ((kg ^ (rb & 7)) << 3)];
      }
#pragma unroll
      for (int i = 0; i < 4; ++i)
#pragma unroll
        for (int j = 0; j < 4; ++j)
          acc[i][j] = mfma16(a[i], bf[j], acc[i][j]);
    }
    __syncthreads();
  }
#pragma unroll
  for (int i = 0; i < 4; ++i) {
#pragma unroll
    for (int j = 0; j < 4; ++j) {
      int n = n0 + wn + j * 16 + (lane & 15);
      float bv = bo[n];
#pragma unroll
      for (int rg = 0; rg < 4; ++rg) {
        int m = m0 + wm + i * 16 + ((lane >> 4) << 2) + rg;
        out[(size_t)m * 1024 + n] = acc[i][j][rg] + bv;
      }
    }
  }
}

// ---------------------------------------------------------------------------
extern "C" void kernel_launch(void* const* d_in, const int* in_sizes, int n_in,
                              void* d_out, int out_size, void* d_ws,
                              size_t ws_size, hipStream_t stream) {
  const float* x    = (const float*)d_in[0];
  const float* mask = (const float*)d_in[1];
  const float* Wqkv = (const float*)d_in[2];
  const float* bqkv = (const float*)d_in[3];
  const float* Wo   = (const float*)d_in[4];
  const float* bo   = (const float*)d_in[5];
  float* out = (float*)d_out;

  char* ws = (char*)d_ws;
  // layout (bytes): xbf 8M | WqkvT 6M | WoT 2M | Qb 8M | Kb 8M | VbT 8M
  // vals aliases xbf (x dead after gemm_qkv). Total 40 MB.
  unsigned short* xbf   = (unsigned short*)(ws);
  unsigned short* WqkvT = (unsigned short*)(ws + 8388608);
  unsigned short* WoT   = (unsigned short*)(ws + 14680064);
  unsigned short* Qb    = (unsigned short*)(ws + 16777216);
  unsigned short* Kb    = (unsigned short*)(ws + 25165824);
  unsigned short* VbT   = (unsigned short*)(ws + 33554432);
  unsigned short* vals  = xbf;  // reuse

  hipLaunchKernelGGL(cvt_x_kernel, dim3(4096), dim3(256), 0, stream,
                     (const float4*)x, (uint2*)xbf, 1048576);
  hipLaunchKernelGGL(transpose_cvt_kernel, dim3(48, 16), dim3(256), 0, stream,
                     Wqkv, WqkvT, 1024, 3072);
  hipLaunchKernelGGL(transpose_cvt_kernel, dim3(16, 16), dim3(256), 0, stream,
                     Wo, WoT, 1024, 1024);
  hipLaunchKernelGGL(gemm_qkv_kernel, dim3(24, 32), dim3(256), 0, stream,
                     xbf, WqkvT, bqkv, Qb, Kb, VbT);
  hipLaunchKernelGGL(attn_kernel, dim3(1024), dim3(256), 0, stream,
                     Qb, Kb, VbT, mask, vals);
  hipLaunchKernelGGL(gemm_out_kernel, dim3(8, 32), dim3(256), 0, stream,
                     vals, WoT, bo, out);
}

// Round 6
// 252.746 us; speedup vs baseline: 1.9365x; 1.0955x over previous
//
#include <hip/hip_runtime.h>
#include <stdint.h>

// ---------------------------------------------------------------------------
// MHA forward, MI355X/gfx950. B=2 S=2048 D=1024 H=16 hd=64.
// Pipeline: cvt x -> bf16 | transpose W's -> bf16 [N][K] | QKV MFMA GEMM ->
// Q/K [bh][s][64] + V^T [bh][64][s] bf16 | flash attn (SWAPPED QK^T: softmax
// lane-local, P->PV in registers via kv-permuted V reads; dbuf K/V; vector
// mask loads; defer-max; deferred row-sum) -> scrambled vals bf16 | out GEMM.
// ---------------------------------------------------------------------------

#define LOG2E 1.44269504088896340736f

typedef __attribute__((ext_vector_type(4))) float f32x4;
typedef __attribute__((ext_vector_type(8))) short short8v;
typedef __attribute__((ext_vector_type(4))) short short4v;
typedef __attribute__((ext_vector_type(8))) __bf16 bf16x8;
typedef __attribute__((ext_vector_type(2))) __bf16 bf16x2;
typedef __attribute__((ext_vector_type(4))) unsigned uint4v;

__device__ __forceinline__ unsigned short f2bf(float f) {
  unsigned u = __builtin_bit_cast(unsigned, f);
  u += 0x7FFFu + ((u >> 16) & 1u);  // RNE
  return (unsigned short)(u >> 16);
}

__device__ __forceinline__ unsigned pack2(float lo, float hi) {
  return (unsigned)f2bf(lo) | ((unsigned)f2bf(hi) << 16);
}

// pack 2 f32 -> 2 bf16 in one u32 (compiler emits v_cvt_pk_bf16_f32)
__device__ __forceinline__ unsigned packbf(float lo, float hi) {
  bf16x2 t;
  t[0] = (__bf16)lo;
  t[1] = (__bf16)hi;
  return __builtin_bit_cast(unsigned, t);
}

__device__ __forceinline__ f32x4 mfma16(short8v a, short8v b, f32x4 c) {
  return __builtin_amdgcn_mfma_f32_16x16x32_bf16(
      __builtin_bit_cast(bf16x8, a), __builtin_bit_cast(bf16x8, b), c, 0, 0, 0);
}

// async global->LDS, 16 bytes per lane. LDS dest = wave-uniform base + lane*16.
__device__ __forceinline__ void gload_lds16(const void* g, void* l) {
  __builtin_amdgcn_global_load_lds(
      (const __attribute__((address_space(1))) void*)(uintptr_t)g,
      (__attribute__((address_space(3))) void*)(uintptr_t)l, 16, 0, 0);
}

// ---------------------------------------------------------------------------
__global__ void cvt_x_kernel(const float4* __restrict__ src,
                             uint2* __restrict__ dst, int n4) {
  int i = blockIdx.x * 256 + threadIdx.x;
  if (i < n4) {
    float4 v = src[i];
    dst[i] = make_uint2(pack2(v.x, v.y), pack2(v.z, v.w));
  }
}

// f32 [R][C] -> bf16 [C][R]
__global__ void transpose_cvt_kernel(const float* __restrict__ src,
                                     unsigned short* __restrict__ dst,
                                     int R, int C) {
  __shared__ unsigned short tile[64][65];
  int tc = threadIdx.x & 63;
  int tr = threadIdx.x >> 6;
  int c0 = blockIdx.x * 64;
  int r0 = blockIdx.y * 64;
#pragma unroll
  for (int i = 0; i < 16; ++i) {
    int r = tr * 16 + i;
    tile[r][tc] = f2bf(src[(size_t)(r0 + r) * C + c0 + tc]);
  }
  __syncthreads();
#pragma unroll
  for (int i = 0; i < 16; ++i) {
    int cc = tr * 16 + i;
    dst[(size_t)(c0 + cc) * R + r0 + tc] = tile[tc][cc];
  }
}

// ---------------------------------------------------------------------------
// QKV GEMM: [4096,1024]bf16 @ WT[3072,1024]bf16 + bias -> Q/K [bh][2048][64],
// V^T [bh][64][2048], all bf16. 128x128 tile, BK=64, 4 waves (2x2 of 64x64).
__global__ __launch_bounds__(256, 2)
void gemm_qkv_kernel(const unsigned short* __restrict__ xbf,
                     const unsigned short* __restrict__ WT,
                     const float* __restrict__ bias,
                     unsigned short* __restrict__ Qb,
                     unsigned short* __restrict__ Kb,
                     unsigned short* __restrict__ VbT) {
  const int K = 1024;
  __shared__ __align__(16) unsigned short As[128 * 64];
  __shared__ __align__(16) unsigned short Bs[128 * 64];
  int tid = threadIdx.x;
  int lane = tid & 63;
  int wid = tid >> 6;
  int m0 = blockIdx.y * 128;
  int n0 = blockIdx.x * 128;
  int wm = (wid >> 1) * 64;
  int wn = (wid & 1) * 64;
  f32x4 acc[4][4] = {};
  for (int k0 = 0; k0 < K; k0 += 64) {
#pragma unroll
    for (int it = 0; it < 4; ++it) {
      int G = it * 256 + tid;
      int r = G >> 3, g = G & 7;
      int sg = g ^ (r & 7);  // inverse-swizzled source, linear LDS dest
      gload_lds16(xbf + (size_t)(m0 + r) * K + k0 + sg * 8, &As[G * 8]);
      gload_lds16(WT + (size_t)(n0 + r) * K + k0 + sg * 8, &Bs[G * 8]);
    }
    __syncthreads();
#pragma unroll
    for (int ks = 0; ks < 2; ++ks) {
      short8v a[4], bf[4];
      int kg = ks * 4 + (lane >> 4);
#pragma unroll
      for (int i = 0; i < 4; ++i) {
        int ra = wm + i * 16 + (lane & 15);
        a[i] = *(const short8v*)&As[ra * 64 + ((kg ^ (ra & 7)) << 3)];
        int rb = wn + i * 16 + (lane & 15);
        bf[i] = *(const short8v*)&Bs[rb * 64 + ((kg ^ (rb & 7)) << 3)];
      }
#pragma unroll
      for (int i = 0; i < 4; ++i)
#pragma unroll
        for (int j = 0; j < 4; ++j)
          acc[i][j] = mfma16(a[i], bf[j], acc[i][j]);
    }
    __syncthreads();
  }
  // epilogue: n -> (h, t, d); t=0 Q, t=1 K, t=2 V(transposed)
#pragma unroll
  for (int i = 0; i < 4; ++i) {
#pragma unroll
    for (int j = 0; j < 4; ++j) {
      int n = n0 + wn + j * 16 + (lane & 15);
      float bv = bias[n];
      int h = n / 192;
      int rr = n - h * 192;
      int t = rr >> 6;
      int d = rr & 63;
#pragma unroll
      for (int rg = 0; rg < 4; ++rg) {
        int m = m0 + wm + i * 16 + ((lane >> 4) << 2) + rg;
        int b = m >> 11, s = m & 2047;
        unsigned short val = f2bf(acc[i][j][rg] + bv);
        int bh = b * 16 + h;
        if (t == 2) {
          VbT[((size_t)bh * 64 + d) * 2048 + s] = val;
        } else {
          unsigned short* dst = (t == 0) ? Qb : Kb;
          dst[((size_t)bh * 2048 + s) * 64 + d] = val;
        }
      }
    }
  }
}

// ---------------------------------------------------------------------------
// Flash attention, swapped QK^T. Block = (b,h,qtile of 64). 4 waves x 16 q.
// Lane (hi=lane>>4, q=lane&15) holds S^T[k=16f+4hi+r][q]: softmax per-lane
// scalar (2 shfls for cross-hi reduce), mask loads are float4, P stays in
// registers (kv-permuted V reads make the PV A-frag register-local).

#define ATTN_STAGE(kt_, bi_)                                                  \
  do {                                                                        \
    _Pragma("unroll") for (int it_ = 0; it_ < 2; ++it_) {                     \
      int G_ = it_ * 256 + tid;                                               \
      int r_ = G_ >> 3, g_ = G_ & 7;                                          \
      int sg_ = g_ ^ (r_ & 7);                                                \
      gload_lds16(Kb + bh_off + (size_t)((kt_)*64 + r_) * 64 + sg_ * 8,       \
                  &Ks[bi_][G_ * 8]);                                          \
      gload_lds16(VbT + bh_off + (size_t)r_ * 2048 + (kt_)*64 + sg_ * 8,      \
                  &Vs[bi_][G_ * 8]);                                          \
    }                                                                         \
  } while (0)

#define ATTN_TILE(kt_, CUR_)                                                  \
  do {                                                                        \
    if ((kt_) < 31) ATTN_STAGE((kt_) + 1, (CUR_) ^ 1);                        \
    /* mask: 4x float4; lane covers k = 16f+4hi+{0..3} of row q */            \
    f32x4 mk_[4];                                                             \
    _Pragma("unroll") for (int f = 0; f < 4; ++f)                             \
        mk_[f] = *(const f32x4*)(mrowq + (size_t)(kt_)*64 + f * 16);          \
    /* swapped QK^T: sf[f][r] = S^T[k=16f+4hi+r][q] */                        \
    f32x4 sf[4] = {};                                                         \
    _Pragma("unroll") for (int ks = 0; ks < 2; ++ks) {                        \
      short8v qa = ks ? qa1 : qa0;                                            \
      int kg = ks * 4 + hi;                                                   \
      _Pragma("unroll") for (int f = 0; f < 4; ++f) {                         \
        int row = f * 16 + lq;                                                \
        short8v kb =                                                          \
            *(const short8v*)&Ks[CUR_][row * 64 + ((kg ^ (row & 7)) << 3)];   \
        sf[f] = mfma16(kb, qa, sf[f]);                                        \
      }                                                                       \
    }                                                                         \
    _Pragma("unroll") for (int f = 0; f < 4; ++f)                             \
        _Pragma("unroll") for (int r = 0; r < 4; ++r)                         \
            sf[f][r] = fmaf(sf[f][r], 0.125f, mk_[f][r]);                     \
    /* per-q tile max: local 15-op tree + 2 shfls over hi bits */             \
    float mx0_ = fmaxf(fmaxf(sf[0][0], sf[0][1]), fmaxf(sf[0][2], sf[0][3])); \
    float mx1_ = fmaxf(fmaxf(sf[1][0], sf[1][1]), fmaxf(sf[1][2], sf[1][3])); \
    float mx2_ = fmaxf(fmaxf(sf[2][0], sf[2][1]), fmaxf(sf[2][2], sf[2][3])); \
    float mx3_ = fmaxf(fmaxf(sf[3][0], sf[3][1]), fmaxf(sf[3][2], sf[3][3])); \
    float mt_ = fmaxf(fmaxf(mx0_, mx1_), fmaxf(mx2_, mx3_));                  \
    mt_ = fmaxf(mt_, __shfl_xor(mt_, 16));                                    \
    mt_ = fmaxf(mt_, __shfl_xor(mt_, 32));                                    \
    /* defer-max */                                                           \
    if (!__all(mt_ <= m_s + THR)) {                                           \
      float mn_ = fmaxf(m_s, mt_);                                            \
      float al_ = exp2f((m_s - mn_) * LOG2E);                                 \
      m_s = mn_;                                                              \
      mLs = mn_ * LOG2E;                                                      \
      l_s *= al_;                                                             \
      float a0_ = __shfl(al_, (lane & 48) | hi4);                             \
      float a1_ = __shfl(al_, (lane & 48) | (hi4 + 1));                       \
      float a2_ = __shfl(al_, (lane & 48) | (hi4 + 2));                       \
      float a3_ = __shfl(al_, (lane & 48) | (hi4 + 3));                       \
      _Pragma("unroll") for (int f = 0; f < 4; ++f) {                         \
        o[f][0] *= a0_; o[f][1] *= a1_; o[f][2] *= a2_; o[f][3] *= a3_;       \
      }                                                                       \
    }                                                                         \
    /* P = exp2(sc*log2e - mLs), pack pairs (consecutive k) to bf16 */        \
    unsigned pk_[4][2];                                                       \
    _Pragma("unroll") for (int f = 0; f < 4; ++f) {                           \
      float p0_ = exp2f(fmaf(sf[f][0], LOG2E, -mLs));                         \
      float p1_ = exp2f(fmaf(sf[f][1], LOG2E, -mLs));                         \
      float p2_ = exp2f(fmaf(sf[f][2], LOG2E, -mLs));                         \
      float p3_ = exp2f(fmaf(sf[f][3], LOG2E, -mLs));                         \
      l_s += (p0_ + p1_) + (p2_ + p3_);                                       \
      pk_[f][0] = packbf(p0_, p1_);                                           \
      pk_[f][1] = packbf(p2_, p3_);                                           \
    }                                                                         \
    /* PV: A-frag = register concat; V read with kv-permutation pi where    */\
    /* slot(8hi+e) -> kv = 32ks + 16*(e>=4) + 4hi + (e&3)                   */\
    _Pragma("unroll") for (int ks = 0; ks < 2; ++ks) {                        \
      uint4v au_;                                                             \
      au_[0] = pk_[2 * ks][0];                                                \
      au_[1] = pk_[2 * ks][1];                                                \
      au_[2] = pk_[2 * ks + 1][0];                                            \
      au_[3] = pk_[2 * ks + 1][1];                                            \
      short8v pa = __builtin_bit_cast(short8v, au_);                          \
      _Pragma("unroll") for (int f = 0; f < 4; ++f) {                         \
        int vrow_ = f * 16 + lq;                                              \
        int blkA_ = 4 * ks + (hi >> 1);                                       \
        int eA_ = vrow_ * 64 + (((blkA_) ^ (vrow_ & 7)) << 3) +               \
                  ((hi & 1) << 2);                                            \
        int eB_ = vrow_ * 64 + (((blkA_ + 2) ^ (vrow_ & 7)) << 3) +           \
                  ((hi & 1) << 2);                                            \
        short4v vlo_ = *(const short4v*)&Vs[CUR_][eA_];                       \
        short4v vhi_ = *(const short4v*)&Vs[CUR_][eB_];                       \
        short8v vb_;                                                          \
        vb_[0] = vlo_[0]; vb_[1] = vlo_[1]; vb_[2] = vlo_[2];                 \
        vb_[3] = vlo_[3]; vb_[4] = vhi_[0]; vb_[5] = vhi_[1];                 \
        vb_[6] = vhi_[2]; vb_[7] = vhi_[3];                                   \
        o[f] = mfma16(pa, vb_, o[f]);                                         \
      }                                                                       \
    }                                                                         \
    __syncthreads();                                                          \
  } while (0)

__global__ __launch_bounds__(256, 4)
void attn_kernel(const unsigned short* __restrict__ Qb,
                 const unsigned short* __restrict__ Kb,
                 const unsigned short* __restrict__ VbT,
                 const float* __restrict__ mask,
                 unsigned short* __restrict__ vals) {
  __shared__ __align__(16) unsigned short Ks[2][64 * 64];
  __shared__ __align__(16) unsigned short Vs[2][64 * 64];
  int tid = threadIdx.x;
  int lane = tid & 63;
  int wid = tid >> 6;
  int lq = lane & 15;
  int hi = lane >> 4;
  int hi4 = hi << 2;
  int h = blockIdx.x & 15;          // h innermost: mask tile L2 reuse
  int qt = (blockIdx.x >> 4) & 31;
  int b = blockIdx.x >> 9;
  int bh = b * 16 + h;
  size_t bh_off = (size_t)bh * 2048 * 64;
  int q0 = qt * 64 + wid * 16;

  const unsigned short* qptr =
      Qb + bh_off + (size_t)(q0 + lq) * 64 + (hi << 3);
  short8v qa0 = *(const short8v*)qptr;
  short8v qa1 = *(const short8v*)(qptr + 32);

  f32x4 o[4] = {};
  float m_s = -1e30f, l_s = 0.f, mLs = 0.f;

  const float* mrowq = mask + ((size_t)b * 2048 + q0 + lq) * 2048 + hi4;

  const float THR = 4.0f;

  ATTN_STAGE(0, 0);
  __syncthreads();

  for (int t = 0; t < 16; ++t) {
    ATTN_TILE(2 * t, 0);
    ATTN_TILE(2 * t + 1, 1);
  }

  // deferred row-sum reduction across hi lanes, then broadcast per o-row
  l_s += __shfl_xor(l_s, 16);
  l_s += __shfl_xor(l_s, 32);
  float ri_ = 1.0f / l_s;
  float rv_[4];
#pragma unroll
  for (int r = 0; r < 4; ++r) rv_[r] = __shfl(ri_, (lane & 48) | (hi4 + r));

  // epilogue: scrambled reshape (b,h,s,d) -> (b, h*128 + s/16, (s%16)*64 + d)
#pragma unroll
  for (int f = 0; f < 4; ++f)
#pragma unroll
    for (int r = 0; r < 4; ++r) {
      int s = q0 + hi4 + r;
      int d = f * 16 + lq;
      int s2 = h * 128 + (s >> 4);
      int c2 = ((s & 15) << 6) + d;
      vals[((size_t)b * 2048 + s2) * 1024 + c2] = f2bf(o[f][r] * rv_[r]);
    }
}

// ---------------------------------------------------------------------------
// Output GEMM: vals[4096,1024]bf16 @ WoT[1024,1024]bf16 + bo -> out f32
__global__ __launch_bounds__(256, 2)
void gemm_out_kernel(const unsigned short* __restrict__ vals,
                     const unsigned short* __restrict__ WoT,
                     const float* __restrict__ bo,
                     float* __restrict__ out) {
  const int K = 1024;
  __shared__ __align__(16) unsigned short As[128 * 64];
  __shared__ __align__(16) unsigned short Bs[128 * 64];
  int tid = threadIdx.x;
  int lane = tid & 63;
  int wid = tid >> 6;
  int m0 = blockIdx.y * 128;
  int n0 = blockIdx.x * 128;
  int wm = (wid >> 1) * 64;
  int wn = (wid & 1) * 64;
  f32x4 acc[4][4] = {};
  for (int k0 = 0; k0 < K; k0 += 64) {
#pragma unroll
    for (int it = 0; it < 4; ++it) {
      int G = it * 256 + tid;
      int r = G >> 3, g = G & 7;
      int sg = g ^ (r & 7);
      gload_lds16(vals + (size_t)(m0 + r) * K + k0 + sg * 8, &As[G * 8]);
      gload_lds16(WoT + (size_t)(n0 + r) * K + k0 + sg * 8, &Bs[G * 8]);
    }
    __syncthreads();
#pragma unroll
    for (int ks = 0; ks < 2; ++ks) {
      short8v a[4], bf[4];
      int kg = ks * 4 + (lane >> 4);
#pragma unroll
      for (int i = 0; i < 4; ++i) {
        int ra = wm + i * 16 + (lane & 15);
        a[i] = *(const short8v*)&As[ra * 64 + ((kg ^ (ra & 7)) << 3)];
        int rb = wn + i * 16 + (lane & 15);
        bf[i] = *(const short8v*)&Bs[rb * 64 + ((kg ^ (rb & 7)) << 3)];
      }
#pragma unroll
      for (int i = 0; i < 4; ++i)
#pragma unroll
        for (int j = 0; j < 4; ++j)
          acc[i][j] = mfma16(a[i], bf[j], acc[i][j]);
    }
    __syncthreads();
  }
#pragma unroll
  for (int i = 0; i < 4; ++i) {
#pragma unroll
    for (int j = 0; j < 4; ++j) {
      int n = n0 + wn + j * 16 + (lane & 15);
      float bv = bo[n];
#pragma unroll
      for (int rg = 0; rg < 4; ++rg) {
        int m = m0 + wm + i * 16 + ((lane >> 4) << 2) + rg;
        out[(size_t)m * 1024 + n] = acc[i][j][rg] + bv;
      }
    }
  }
}

// ---------------------------------------------------------------------------
extern "C" void kernel_launch(void* const* d_in, const int* in_sizes, int n_in,
                              void* d_out, int out_size, void* d_ws,
                              size_t ws_size, hipStream_t stream) {
  const float* x    = (const float*)d_in[0];
  const float* mask = (const float*)d_in[1];
  const float* Wqkv = (const float*)d_in[2];
  const float* bqkv = (const float*)d_in[3];
  const float* Wo   = (const float*)d_in[4];
  const float* bo   = (const float*)d_in[5];
  float* out = (float*)d_out;

  char* ws = (char*)d_ws;
  // layout (bytes): xbf 8M | WqkvT 6M | WoT 2M | Qb 8M | Kb 8M | VbT 8M
  // vals aliases xbf (x dead after gemm_qkv). Total 40 MB.
  unsigned short* xbf   = (unsigned short*)(ws);
  unsigned short* WqkvT = (unsigned short*)(ws + 8388608);
  unsigned short* WoT   = (unsigned short*)(ws + 14680064);
  unsigned short* Qb    = (unsigned short*)(ws + 16777216);
  unsigned short* Kb    = (unsigned short*)(ws + 25165824);
  unsigned short* VbT   = (unsigned short*)(ws + 33554432);
  unsigned short* vals  = xbf;  // reuse

  hipLaunchKernelGGL(cvt_x_kernel, dim3(4096), dim3(256), 0, stream,
                     (const float4*)x, (uint2*)xbf, 1048576);
  hipLaunchKernelGGL(transpose_cvt_kernel, dim3(48, 16), dim3(256), 0, stream,
                     Wqkv, WqkvT, 1024, 3072);
  hipLaunchKernelGGL(transpose_cvt_kernel, dim3(16, 16), dim3(256), 0, stream,
                     Wo, WoT, 1024, 1024);
  hipLaunchKernelGGL(gemm_qkv_kernel, dim3(24, 32), dim3(256), 0, stream,
                     xbf, WqkvT, bqkv, Qb, Kb, VbT);
  hipLaunchKernelGGL(attn_kernel, dim3(1024), dim3(256), 0, stream,
                     Qb, Kb, VbT, mask, vals);
  hipLaunchKernelGGL(gemm_out_kernel, dim3(8, 32), dim3(256), 0, stream,
                     vals, WoT, bo, out);
}